// Round 5
// baseline (118.688 us; speedup 1.0000x reference)
//
#include <hip/hip_runtime.h>
#include <math.h>

// Counted-vmcnt pipelined span IIR (z-formulation):
//   z[i] = alpha*z[i-1] + d[i];  y[i] = d[i] - (1-alpha)*z[i-1]
// R5: break phase lockstep. R1/R3/R4 (three different barrier structures)
// all plateau at ~33us = 4.1 TB/s eff vs 22us floor -> the invariant is
// bulk-synchronous phases: read burst / VALU / store burst never overlap.
// This version software-pipelines chunks with counted waits (T3/T4):
//   per chunk: s_waitcnt vmcnt(2) -> scan chunk c (LDS+DPP) -> issue
//   stage(c+1) (global_load_lds) -> lgkmcnt(0) + raw s_barrier -> compose
//   -> phase C + 2 nontemporal stores.
// Key invariants:
//  * LDS data plane is per-wave-private (wave stages/reads only its own
//    region) -> buffer readiness needs NO barrier, only per-wave vmcnt.
//  * Issue order stage(c+1) THEN stores(c) => vmcnt(2) at next top == "stage
//    done, 2 stores still in flight". Stores drain under the next scan.
//  * wtot is double-buffered; one s_barrier (lgkmcnt only!) per chunk is
//    sufficient: iter c+2's wtot[par] write can only happen after all waves
//    passed barrier c+1, i.e. after all iter-c reads of wtot[par].
// Span = 8 chunks of 4096 (32768 out elems/block); halo paid once per span
// (read amp 6.25%). Grid = 8 x 64 = 512 blocks = 2 blocks/CU. LDS 32.9 KB.
#define TPB 512
#define WAVES 8
#define PER_WAVE 512              // floats per wave per chunk (2 sub-blocks)
#define CHUNK 4096                // floats = 16 KB
#define CPB 8                     // chunks per block
#define HALO 2048                 // alpha^2048 ~ 2.9e-3 << 0.1075 threshold

typedef float v4f __attribute__((ext_vector_type(4)));

template<int CTRL, int RM, int BM, bool BC>
__device__ __forceinline__ float dppf(float v) {
    return __int_as_float(__builtin_amdgcn_update_dpp(
        0, __float_as_int(v), CTRL, RM, BM, BC));
}

__device__ __forceinline__ float readlane_f(float v, int l) {
    return __int_as_float(__builtin_amdgcn_readlane(__float_as_int(v), l));
}

// global -> LDS direct copy, 16B/lane. LDS dest is wave-uniform base
// (+ lane*16 by HW); global src per-lane. Linear both sides. vmcnt op.
__device__ __forceinline__ void stage16(const float* __restrict__ g, float* l) {
    __builtin_amdgcn_global_load_lds(
        (const __attribute__((address_space(1))) unsigned int*)g,
        (__attribute__((address_space(3))) unsigned int*)l, 16, 0, 0);
}

// Weighted inclusive scan over 64 lanes: S_l = sum_{k<=l} m^(l-k) * v_k, m=A4.
// row_shr 1/2/4/8 (within-16), row_bcast:15 (rows 1,3 += w1 * prev-row
// prefix), row_bcast:31 (rows 2,3 += w2 * S_31).
__device__ __forceinline__ float scan_iir(float v, float mo1, float mo2,
                                          float mo4, float mo8,
                                          float w1, float w2) {
    float b;
    b = dppf<0x111, 0xF, 0xF, true >(v); v = fmaf(mo1, b, v); // row_shr:1
    b = dppf<0x112, 0xF, 0xF, true >(v); v = fmaf(mo2, b, v); // row_shr:2
    b = dppf<0x114, 0xF, 0xF, true >(v); v = fmaf(mo4, b, v); // row_shr:4
    b = dppf<0x118, 0xF, 0xF, true >(v); v = fmaf(mo8, b, v); // row_shr:8
    b = dppf<0x142, 0xA, 0xF, false>(v); v = fmaf(w1,  b, v); // row_bcast:15
    b = dppf<0x143, 0xC, 0xF, false>(v); v = fmaf(w2,  b, v); // row_bcast:31
    return v;
}

__device__ __forceinline__ float shape(float xs, int ty, float g, float dc,
                                       float c1, float c0) {
    if (ty == 0) {
        // tanh(p) = 1 - 2/(exp(2p)+1), exp folded: e2 = 2^(xs*c1 + c0)
        float e2 = __builtin_amdgcn_exp2f(fmaf(xs, c1, c0));
        return fmaf(-2.0f, __builtin_amdgcn_rcpf(e2 + 1.0f), 1.0f);
    }
    float p = (xs + dc) * g;
    if (ty == 1) {
        return fminf(fmaxf(p, -1.0f), 1.0f);
    } else if (ty == 2) {
        float r = p + 1.0f;
        float rem = r - 4.0f * floorf(r * 0.25f);   // jnp.remainder(r, 4)
        return fabsf(rem - 2.0f) - 1.0f;
    } else if (ty == 3) {
        return __sinf(p * 1.5707963267948966f);
    } else {
        return p / (1.0f + fabsf(p));
    }
}

__global__ void __launch_bounds__(TPB, 4)
dist_kernel(const float* __restrict__ x,
            const float* __restrict__ drive,
            const float* __restrict__ bias,
            const float* __restrict__ mix,
            const int* __restrict__ type_idx,
            float* __restrict__ out,
            int N, float alpha, float beta)
{
    const int row  = blockIdx.y;
    const int bx   = blockIdx.x;
    const int tid  = threadIdx.x;
    const int lane = tid & 63;
    const int wv   = tid >> 6;
    const int ty   = *type_idx;   // wave-uniform

    const int nChunks = (N + CHUNK - 1) / CHUNK;
    const int cFirst = bx * CPB;
    if (cFirst >= nChunks) return;              // uniform whole-block exit
    const int cLast = min(cFirst + CPB, nChunks);
    const int spanStart = cFirst * CHUNK;

    const long long rowBase = (long long)row * (long long)N;
    const float* __restrict__ xr = x + rowBase;
    float* __restrict__ outr = out + rowBase;

    __shared__ float sbuf[2][CHUNK];
    __shared__ float wtot[2][WAVES];
    __shared__ float htot[WAVES];

    const int wb = wv * PER_WAVE;         // wave-uniform base within chunk
    const int lo = wb + lane * 4;         // per-lane offset within chunk

    // ---- prologue: halo load first (oldest vmcnt), then stage chunk 0 ----
    v4f hx;
    const bool haveHalo = (bx > 0);
    if (haveHalo) {
        const int j = spanStart - HALO + wv * 256 + lane * 4;  // in-bounds
        hx = *reinterpret_cast<const v4f*>(xr + j);
    }
    if (spanStart + CHUNK <= N) {
        stage16(xr + spanStart + lo,       &sbuf[0][wb]);
        stage16(xr + spanStart + lo + 256, &sbuf[0][wb + 256]);
    } else {
        #pragma unroll
        for (int h = 0; h < 2; ++h) {
            const int idx = lo + h * 256;
            const int j = spanStart + idx;
            v4f v;
            v.x = (j + 0 < N) ? xr[j + 0] : 0.0f;
            v.y = (j + 1 < N) ? xr[j + 1] : 0.0f;
            v.z = (j + 2 < N) ? xr[j + 2] : 0.0f;
            v.w = (j + 3 < N) ? xr[j + 3] : 0.0f;
            *reinterpret_cast<v4f*>(&sbuf[0][idx]) = v;
        }
    }

    // row params + constants (overlap with load flight)
    const float g  = exp2f(drive[row] * 7.972672880099267f);  // 10^(2.4*drive)
    const float dc = bias[row] * 2.0f - 1.0f;
    const float mm = mix[row];
    const float om = 1.0f - mm;
    const float c1 = g * 2.8853900817779268f;   // 2*log2(e)*g
    const float c0 = dc * c1;

    const float A2 = alpha * alpha;
    const float A4 = A2 * A2;
    const float A8 = A4 * A4;
    const float A16 = A8 * A8;
    const float A32 = A16 * A16;
    const float A64 = A32 * A32;
    const float A128 = A64 * A64;
    const float A256 = A128 * A128;
    const float A512 = A256 * A256;

    // per-lane multipliers: p15 = A4^(lane&15), apl = A4^lane
    float p15 = 1.0f;
    {
        float b = A4; const int n = lane & 15;
        #pragma unroll
        for (int i = 0; i < 4; ++i) { if ((n >> i) & 1) p15 *= b; b *= b; }
    }
    const float p31 = (lane & 16) ? p15 * A64  : p15;   // A4^(lane&31)
    const float apl = (lane & 32) ? p31 * A128 : p31;   // A4^lane
    const float w1 = A4 * p15;                          // A4^((lane&15)+1)
    const float w2 = A4 * p31;                          // A4^((lane&31)+1)

    // ---- halo scan: wave w scans halo sub-block w (256 floats) ----
    float carry = 0.0f;
    if (haveHalo) {
        float r = shape(hx.x, ty, g, dc, c1, c0);
        r = fmaf(alpha, r, shape(hx.y, ty, g, dc, c1, c0));
        r = fmaf(alpha, r, shape(hx.z, ty, g, dc, c1, c0));
        r = fmaf(alpha, r, shape(hx.w, ty, g, dc, c1, c0));
        const float s = scan_iir(r, A4, A8, A16, A32, w1, w2);
        if (lane == 63) htot[wv] = s;
        asm volatile("s_waitcnt lgkmcnt(0)" ::: "memory");
        __builtin_amdgcn_s_barrier();               // publish htot (no vmcnt)
        __builtin_amdgcn_sched_barrier(0);
        const v4f h0 = *reinterpret_cast<const v4f*>(&htot[0]);
        const v4f h1 = *reinterpret_cast<const v4f*>(&htot[4]);
        carry = h0.x;
        carry = fmaf(A256, carry, h0.y);
        carry = fmaf(A256, carry, h0.z);
        carry = fmaf(A256, carry, h0.w);
        carry = fmaf(A256, carry, h1.x);
        carry = fmaf(A256, carry, h1.y);
        carry = fmaf(A256, carry, h1.z);
        carry = fmaf(A256, carry, h1.w);
    }

    // drain prologue vmem once: chunk 0 resident before first scan
    asm volatile("s_waitcnt vmcnt(0)" ::: "memory");
    __builtin_amdgcn_sched_barrier(0);

    // ---- pipelined main loop ----
    int par = 0;
    for (int c = cFirst; c < cLast; ++c, par ^= 1) {
        // per-wave buffer readiness: stage(c) was issued before stores(c-1),
        // so <=2 outstanding => stage(c) complete (stores may still fly)
        asm volatile("s_waitcnt vmcnt(2)" ::: "memory");
        __builtin_amdgcn_sched_barrier(0);

        // phase A: scan chunk c from LDS (own region only)
        float iv[2], Tk[2];
        #pragma unroll
        for (int k = 0; k < 2; ++k) {
            const v4f xv = *reinterpret_cast<const v4f*>(&sbuf[par][lo + k * 256]);
            float acc = shape(xv.x, ty, g, dc, c1, c0);
            acc = fmaf(alpha, acc, shape(xv.y, ty, g, dc, c1, c0));
            acc = fmaf(alpha, acc, shape(xv.z, ty, g, dc, c1, c0));
            acc = fmaf(alpha, acc, shape(xv.w, ty, g, dc, c1, c0));
            iv[k] = scan_iir(acc, A4, A8, A16, A32, w1, w2);
            Tk[k] = readlane_f(iv[k], 63);
        }
        if (lane == 0) wtot[par][wv] = fmaf(A256, Tk[0], Tk[1]);

        // issue stage(c+1) into the other buffer (read last in iter c-1;
        // this wave's ds_reads of it completed before its last use -> safe)
        if (c + 1 < cLast) {
            const int nb = (c + 1) * CHUNK;
            if (nb + CHUNK <= N) {
                stage16(xr + nb + lo,       &sbuf[par ^ 1][wb]);
                stage16(xr + nb + lo + 256, &sbuf[par ^ 1][wb + 256]);
            } else {
                #pragma unroll
                for (int h = 0; h < 2; ++h) {
                    const int idx = lo + h * 256;
                    const int j = nb + idx;
                    v4f v;
                    v.x = (j + 0 < N) ? xr[j + 0] : 0.0f;
                    v.y = (j + 1 < N) ? xr[j + 1] : 0.0f;
                    v.z = (j + 2 < N) ? xr[j + 2] : 0.0f;
                    v.w = (j + 3 < N) ? xr[j + 3] : 0.0f;
                    *reinterpret_cast<v4f*>(&sbuf[par ^ 1][idx]) = v;
                }
            }
        }

        // one barrier per chunk: publish wtot[par] (lgkmcnt only, NO vmcnt
        // drain -> stage loads and stores stay in flight across it)
        asm volatile("s_waitcnt lgkmcnt(0)" ::: "memory");
        __builtin_amdgcn_s_barrier();
        __builtin_amdgcn_sched_barrier(0);

        // compose: P = z entering this wave; carry -> z entering chunk c+1
        const v4f t0 = *reinterpret_cast<const v4f*>(&wtot[par][0]);
        const v4f t1 = *reinterpret_cast<const v4f*>(&wtot[par][4]);
        const float ww[8] = {t0.x, t0.y, t0.z, t0.w, t1.x, t1.y, t1.z, t1.w};
        float P = carry;
        #pragma unroll
        for (int w = 0; w < 7; ++w)
            if (w < wv) P = fmaf(A512, P, ww[w]);
        #pragma unroll
        for (int w = 0; w < 8; ++w)
            carry = fmaf(A512, carry, ww[w]);

        // phase C: y[i] = d[i] - beta*z[i-1]; out = om*x + mm*y
        #pragma unroll
        for (int k = 0; k < 2; ++k) {
            const int j = c * CHUNK + lo + k * 256;
            const v4f xv = *reinterpret_cast<const v4f*>(&sbuf[par][lo + k * 256]);
            const float d0 = shape(xv.x, ty, g, dc, c1, c0);
            const float d1 = shape(xv.y, ty, g, dc, c1, c0);
            const float d2 = shape(xv.z, ty, g, dc, c1, c0);
            const float d3 = shape(xv.w, ty, g, dc, c1, c0);
            const float Ck = (k == 0) ? P : fmaf(A256, P, Tk[0]);
            // exclusive lane scan = previous lane's inclusive (lane0 -> 0)
            const float ex = dppf<0x138, 0xF, 0xF, true>(iv[k]); // wave_shr:1
            float z = fmaf(apl, Ck, ex);                  // z before lane's run
            v4f ov; float y;
            y = fmaf(-beta, z, d0); ov.x = fmaf(mm, y, om * xv.x); z = fmaf(alpha, z, d0);
            y = fmaf(-beta, z, d1); ov.y = fmaf(mm, y, om * xv.y); z = fmaf(alpha, z, d1);
            y = fmaf(-beta, z, d2); ov.z = fmaf(mm, y, om * xv.z); z = fmaf(alpha, z, d2);
            y = fmaf(-beta, z, d3); ov.w = fmaf(mm, y, om * xv.w);
            if (j + 4 <= N) {
                __builtin_nontemporal_store(ov, reinterpret_cast<v4f*>(outr + j));
            } else {
                if (j + 0 < N) outr[j + 0] = ov.x;
                if (j + 1 < N) outr[j + 1] = ov.y;
                if (j + 2 < N) outr[j + 2] = ov.z;
                if (j + 3 < N) outr[j + 3] = ov.w;
            }
        }
    }
    // stores drain as the block retires (no trailing barrier)
}

extern "C" void kernel_launch(void* const* d_in, const int* in_sizes, int n_in,
                              void* d_out, int out_size, void* d_ws, size_t ws_size,
                              hipStream_t stream) {
    const float* x     = (const float*)d_in[0];
    const float* drive = (const float*)d_in[1];
    const float* bias  = (const float*)d_in[2];
    const float* mixp  = (const float*)d_in[3];
    const int*   tyi   = (const int*)d_in[4];
    float* out = (float*)d_out;

    const int B = in_sizes[1];              // drive is (B,1)
    const int N = in_sizes[0] / B;

    const double alpha_d = exp(-2.0 * M_PI * 20.0 / 44100.0);
    const float alpha = (float)alpha_d;
    const float beta  = (float)(1.0 - alpha_d);

    const int nChunks = (N + CHUNK - 1) / CHUNK;
    const int nSpans = (nChunks + CPB - 1) / CPB;
    dim3 grid(nSpans, B);
    dist_kernel<<<grid, TPB, 0, stream>>>(x, drive, bias, mixp, tyi, out, N, alpha, beta);
}